// Round 9
// baseline (162.940 us; speedup 1.0000x reference)
//
#include <hip/hip_runtime.h>

constexpr int TPB   = 256;    // generic block
constexpr int NMAX  = 16384;  // fast-path cap (node ids fit 20 bits, rloc 6 bits)
constexpr int CHUNK = 1024;   // edges per k_p1 block
constexpr int GBMAX = 1024;   // fast-path cap on p1 grid (E <= 1M edges)
constexpr int P2CAP = 10240;  // staged entries per bucket in k_p2 (80 KB LDS)

// edge_index delivered as int32 [2][E] (validated R3 counters + R6 pass).

// ============ fast path: two-level bucket CSR build, coalesced writes ============
// bucket = node >> rsh (RN = 1<<rsh <= 64 nodes/bucket, NBe = ceil(N/RN) <= 256)
// Per-(block,bucket) tables stored TRANSPOSED [k*GB + b] so column ops are contiguous.

// ---- p1: partition edge-endpoint entries into per-(block,bucket) runs in tmp ----
__global__ __launch_bounds__(1024) void k_p1(const int* __restrict__ ei,
    const float* __restrict__ ew, int E, int rsh, int NBe, int GB,
    int* __restrict__ bstartT, int* __restrict__ bcntT, int2* __restrict__ tmp) {
    __shared__ int cnt[256];
    __shared__ int curs[256];
    __shared__ int sc[256];
    __shared__ int2 stg[2 * CHUNK];   // 16 KB
    int tid = threadIdx.x;
    int b = blockIdx.x;
    int e0 = b * CHUNK;
    int e1 = min(E, e0 + CHUNK);
    if (tid < NBe) cnt[tid] = 0;
    __syncthreads();
    int e = e0 + tid;
    bool va = e < e1;
    int r = 0, c = 0, w = 0;
    if (va) {
        r = ei[e]; c = ei[E + e]; w = __float_as_int(0.5f * ew[e]);
        atomicAdd(&cnt[r >> rsh], 1);
        atomicAdd(&cnt[c >> rsh], 1);
    }
    __syncthreads();
    int myc = (tid < NBe) ? cnt[tid] : 0;
    if (tid < NBe) sc[tid] = myc;
    __syncthreads();
    for (int off = 1; off < NBe; off <<= 1) {
        int v = 0;
        if (tid < NBe && tid >= off) v = sc[tid - off];
        __syncthreads();
        if (tid < NBe) sc[tid] += v;
        __syncthreads();
    }
    if (tid < NBe) {
        int excl = sc[tid] - myc;
        curs[tid] = excl;
        bstartT[tid * GB + b] = 2 * e0 + excl;   // transposed
        bcntT[tid * GB + b] = myc;
    }
    __syncthreads();
    int mask = (1 << rsh) - 1;
    if (va) {
        int p = atomicAdd(&curs[r >> rsh], 1);
        stg[p] = make_int2(((r & mask) << 20) | c, w);
        p = atomicAdd(&curs[c >> rsh], 1);
        stg[p] = make_int2(((c & mask) << 20) | r, w);
    }
    __syncthreads();
    int tot = 2 * (e1 - e0);
    for (int i = tid; i < tot; i += 1024) tmp[2 * e0 + i] = stg[i];  // coalesced burst
}

// ---- colsum: one block per bucket, contiguous coalesced row sum -> btot[k] ----
__global__ void k_colsum(const int* __restrict__ bcntT, int GB,
                         int* __restrict__ btot) {
    __shared__ int red[TPB / 64];
    int k = blockIdx.x;
    int s = 0;
    for (int b = threadIdx.x; b < GB; b += TPB) s += bcntT[k * GB + b];
    #pragma unroll
    for (int off = 32; off; off >>= 1) s += __shfl_down(s, off, 64);
    int wv = threadIdx.x >> 6;
    if ((threadIdx.x & 63) == 0) red[wv] = s;
    __syncthreads();
    if (threadIdx.x == 0) {
        int t = 0;
        for (int w = 0; w < TPB / 64; ++w) t += red[w];
        btot[k] = t;
    }
}

// ---- p2: per-bucket single-pass sort via LDS staging -> CSR + rowptr + dis ----
__global__ __launch_bounds__(1024) void k_p2(const int2* __restrict__ tmp,
    const int* __restrict__ bstartT, const int* __restrict__ bcntT,
    const int* __restrict__ btot, int GB, int rsh, int N, int NBe, int M,
    int2* __restrict__ ent, int* __restrict__ rowptr, float* __restrict__ dis) {
    __shared__ int sco[256];        // btot scan -> entBase
    __shared__ int segoff[GBMAX];   // per-segment staging offsets
    __shared__ int ncnt[64];
    __shared__ int nstart[64];
    __shared__ int ncur[64];
    __shared__ float wsum[64];
    __shared__ int2 stg[P2CAP];     // 80 KB
    int k = blockIdx.x;
    int tid = threadIdx.x;
    int RN = 1 << rsh;
    int n0 = k << rsh;
    // entBase: exclusive scan of btot (all blocks do it locally; 1 KB, cheap)
    int bt = (tid < NBe) ? btot[tid] : 0;
    if (tid < 256) sco[tid] = bt;
    __syncthreads();
    for (int off = 1; off < 256; off <<= 1) {
        int v = 0;
        if (tid < 256 && tid >= off) v = sco[tid - off];
        __syncthreads();
        if (tid < 256) sco[tid] += v;
        __syncthreads();
    }
    int btotk = btot[k];
    int eb = sco[k] - btotk;          // exclusive prefix
    if (tid < RN) { ncnt[tid] = 0; wsum[tid] = 0.f; }
    // segment lengths -> staging offsets (one segment per thread; GB <= 1024)
    int l = (tid < GB) ? bcntT[k * GB + tid] : 0;
    int s = (tid < GB) ? bstartT[k * GB + tid] : 0;
    if (tid < GB) segoff[tid] = l;
    __syncthreads();
    for (int off = 1; off < GB; off <<= 1) {
        int v = 0;
        if (tid < GB && tid >= off) v = segoff[tid - off];
        __syncthreads();
        if (tid < GB) segoff[tid] += v;
        __syncthreads();
    }
    int excl = (tid < GB) ? (segoff[tid] - l) : 0;
    // Phase A: read tmp once: histogram + stage
    for (int u = 0; u < l; ++u) {
        int2 v = tmp[s + u];
        atomicAdd(&ncnt[v.x >> 20], 1);
        int pos = excl + u;
        if (pos < P2CAP) stg[pos] = v;
    }
    __syncthreads();
    // node-local exclusive scan
    int myc = (tid < RN) ? ncnt[tid] : 0;
    if (tid < RN) nstart[tid] = myc;
    __syncthreads();
    for (int off = 1; off < RN; off <<= 1) {
        int v = 0;
        if (tid < RN && tid >= off) v = nstart[tid - off];
        __syncthreads();
        if (tid < RN) nstart[tid] += v;
        __syncthreads();
    }
    if (tid < RN) { nstart[tid] -= myc; ncur[tid] = nstart[tid]; }
    __syncthreads();
    // Phase B: scatter staged entries into bucket's contiguous CSR region
    int staged = min(btotk, P2CAP);
    for (int i = tid; i < staged; i += 1024) {
        int2 v = stg[i];
        int rl = v.x >> 20;
        int cc = v.x & 0xFFFFF;
        int p = atomicAdd(&ncur[rl], 1);
        ent[eb + p] = make_int2(cc, v.y);
        atomicAdd(&wsum[rl], __int_as_float(v.y));
    }
    // rare overflow: entries beyond P2CAP re-read from global
    if (btotk > P2CAP && excl + l > P2CAP) {
        for (int u = 0; u < l; ++u) {
            int pos = excl + u;
            if (pos >= P2CAP) {
                int2 v = tmp[s + u];
                int rl = v.x >> 20;
                int cc = v.x & 0xFFFFF;
                int p = atomicAdd(&ncur[rl], 1);
                ent[eb + p] = make_int2(cc, v.y);
                atomicAdd(&wsum[rl], __int_as_float(v.y));
            }
        }
    }
    __syncthreads();
    if (tid < RN && n0 + tid < N) {
        rowptr[n0 + tid] = eb + nstart[tid];
        dis[n0 + tid] = rsqrtf(1.f + wsum[tid]);
    }
    if (k == 0 && tid == 0) rowptr[N] = M;
}

// ============ fallback path: global-atomic prep ============
__global__ void k_init_fb(float* deg, int* counts, int N) {
    int i = blockIdx.x * TPB + threadIdx.x;
    if (i < N) { deg[i] = 1.0f; counts[i] = 0; }
}
__global__ void k_deg_cnt_fb(const int* __restrict__ ei, const float* __restrict__ ew,
                             float* deg, int* counts, int E) {
    int e = blockIdx.x * TPB + threadIdx.x;
    if (e >= E) return;
    int r = ei[e], c = ei[E + e];
    float hw = 0.5f * ew[e];
    unsafeAtomicAdd(&deg[r], hw);
    unsafeAtomicAdd(&deg[c], hw);
    atomicAdd(&counts[r], 1);
    atomicAdd(&counts[c], 1);
}
__global__ void k_rsqrt_fb(float* degdis, int N) {
    int i = blockIdx.x * TPB + threadIdx.x;
    if (i < N) {
        float d = degdis[i];
        degdis[i] = d > 0.f ? rsqrtf(d) : 0.f;
    }
}
__global__ void k_scan_fb(const int* __restrict__ counts, int* __restrict__ rowptr,
                          int* __restrict__ cursor, int N) {
    __shared__ int partial[TPB];
    int tid = threadIdx.x;
    int chunk = (N + TPB - 1) / TPB;
    int begin = tid * chunk;
    int end = begin + chunk; if (end > N) end = N;
    int s = 0;
    for (int i = begin; i < end; ++i) s += counts[i];
    partial[tid] = s;
    __syncthreads();
    for (int off = 1; off < TPB; off <<= 1) {
        int v = partial[tid];
        int add = (tid >= off) ? partial[tid - off] : 0;
        __syncthreads();
        partial[tid] = v + add;
        __syncthreads();
    }
    int base = (tid == 0) ? 0 : partial[tid - 1];
    for (int i = begin; i < end; ++i) {
        rowptr[i] = base; cursor[i] = base;
        base += counts[i];
    }
    if (tid == TPB - 1) rowptr[N] = base;
}
__global__ void k_fill_fb(const int* __restrict__ ei, const float* __restrict__ ew,
                          int* cursor, int2* __restrict__ ent, int E) {
    int e = blockIdx.x * TPB + threadIdx.x;
    if (e >= E) return;
    int r = ei[e], c = ei[E + e];
    int hw = __float_as_int(0.5f * ew[e]);
    int p1 = atomicAdd(&cursor[r], 1);
    ent[p1] = make_int2(c, hw);
    int p2 = atomicAdd(&cursor[c], 1);
    ent[p2] = make_int2(r, hw);
}

// ---------------- Z1[N,64] = dis .* (X[N,64] @ W1[64,64]) ----------------
__global__ void k_gemm1(const float* __restrict__ X, const float* __restrict__ W,
                        const float* __restrict__ dis, float* __restrict__ Z, int N) {
    __shared__ float Wl[64 * 64];
    int tid = threadIdx.x;
    #pragma unroll
    for (int i = tid; i < 4096; i += TPB) Wl[i] = W[i];
    __syncthreads();
    int row = blockIdx.x * 4 + (tid >> 6);
    int f = tid & 63;
    if (row >= N) return;
    const float* xr = X + row * 64;
    float s = 0.f;
    #pragma unroll
    for (int k = 0; k < 64; ++k) s = fmaf(xr[k], Wl[k * 64 + f], s);
    Z[row * 64 + f] = dis[row] * s;
}

// ---- gather: float4 lanes (D/4 lanes per node), pipelined tiles, shuffle bcast ----
template <int D, bool RELU>
__global__ void k_gather(const float* __restrict__ Z, const int* __restrict__ rowptr,
                         const long long* __restrict__ entq, const float* __restrict__ dis,
                         const float* __restrict__ bias, float* __restrict__ out, int N) {
    constexpr int LPN = D / 4;                 // lanes per node
    constexpr int UN = (LPN >= 8) ? 8 : LPN;   // inner unroll
    int tid = threadIdx.x;
    int lane = tid & 63;
    int node = blockIdx.x * (TPB / LPN) + tid / LPN;
    int fq = lane & (LPN - 1);
    int base = lane - fq;                      // node group's first lane in wave
    if (node >= N) return;
    int j0 = rowptr[node], j1 = rowptr[node + 1];
    const float4* Z4 = (const float4*)Z;
    float4 acc = Z4[node * LPN + fq];
    long long cur = 0;
    if (j0 < j1) cur = __builtin_nontemporal_load(entq + j0 + fq);  // ent padded
    for (int jb = j0; jb < j1; jb += LPN) {
        long long nxt = cur;
        if (jb + LPN < j1) nxt = __builtin_nontemporal_load(entq + jb + LPN + fq);
        int ex = (int)cur;
        float ey = __int_as_float((int)(cur >> 32));
        int cnt = j1 - jb; if (cnt > LPN) cnt = LPN;
        int k = 0;
        for (; k + UN <= cnt; k += UN) {
            int n[UN]; float w[UN]; float4 z[UN];
            #pragma unroll
            for (int u = 0; u < UN; ++u) {
                n[u] = __shfl(ex, base + k + u);
                w[u] = __shfl(ey, base + k + u);
            }
            #pragma unroll
            for (int u = 0; u < UN; ++u) z[u] = Z4[n[u] * LPN + fq];
            #pragma unroll
            for (int u = 0; u < UN; ++u) {
                acc.x = fmaf(w[u], z[u].x, acc.x);
                acc.y = fmaf(w[u], z[u].y, acc.y);
                acc.z = fmaf(w[u], z[u].z, acc.z);
                acc.w = fmaf(w[u], z[u].w, acc.w);
            }
        }
        for (; k < cnt; ++k) {
            int n0 = __shfl(ex, base + k);
            float w0 = __shfl(ey, base + k);
            float4 z = Z4[n0 * LPN + fq];
            acc.x = fmaf(w0, z.x, acc.x);
            acc.y = fmaf(w0, z.y, acc.y);
            acc.z = fmaf(w0, z.z, acc.z);
            acc.w = fmaf(w0, z.w, acc.w);
        }
        cur = nxt;
    }
    float d = dis[node];
    float4 bb = ((const float4*)bias)[fq];
    float4 v;
    v.x = fmaf(d, acc.x, bb.x);
    v.y = fmaf(d, acc.y, bb.y);
    v.z = fmaf(d, acc.z, bb.z);
    v.w = fmaf(d, acc.w, bb.w);
    if (RELU) {
        v.x = v.x > 0.f ? v.x : 0.f;
        v.y = v.y > 0.f ? v.y : 0.f;
        v.z = v.z > 0.f ? v.z : 0.f;
        v.w = v.w > 0.f ? v.w : 0.f;
    }
    ((float4*)out)[node * LPN + fq] = v;
}

// ---------------- Z2[N,16] = dis .* (H[N,64] @ W2[64,16]) ----------------
__global__ void k_gemm2(const float* __restrict__ H, const float* __restrict__ W2,
                        const float* __restrict__ dis, float* __restrict__ Z2, int N) {
    __shared__ float Wl[64 * 16];
    int tid = threadIdx.x;
    #pragma unroll
    for (int i = tid; i < 1024; i += TPB) Wl[i] = W2[i];
    __syncthreads();
    int row = blockIdx.x * 16 + (tid >> 4);
    int f = tid & 15;
    if (row >= N) return;
    const float* hr = H + row * 64;
    float s = 0.f;
    #pragma unroll
    for (int k = 0; k < 64; ++k) s = fmaf(hr[k], Wl[k * 16 + f], s);
    Z2[row * 16 + f] = dis[row] * s;
}

extern "C" void kernel_launch(void* const* d_in, const int* in_sizes, int n_in,
                              void* d_out, int out_size, void* d_ws, size_t ws_size,
                              hipStream_t stream) {
    const float* x  = (const float*)d_in[0];
    const float* W1 = (const float*)d_in[1];
    const float* b1 = (const float*)d_in[2];
    const float* W2 = (const float*)d_in[3];
    const float* b2 = (const float*)d_in[4];
    const float* ew = (const float*)d_in[5];
    const int*   ei = (const int*)d_in[6];   // int32 layout (validated)

    const int N = in_sizes[0] / 64;   // 16384
    const int E = in_sizes[5];        // 524288
    const int M = 2 * E;              // CSR entries

    // bucket geometry: RN = pow2 <= 64, NBe = ceil(N/RN) <= 256
    int rsh = 0;
    while ((256 << rsh) < N) ++rsh;
    const int NBe = (N + (1 << rsh) - 1) >> rsh;
    const int GB  = (E + CHUNK - 1) / CHUNK;

    char* ws = (char*)d_ws;
    size_t off = 0;
    auto alloc = [&](size_t bytes) -> void* {
        void* p = ws + off;
        off += (bytes + 255) & ~(size_t)255;
        return p;
    };
    float* dis     = (float*)alloc((size_t)N * 4);
    int*   counts  = (int*)alloc((size_t)N * 4);          // fallback only
    int*   rowptr  = (int*)alloc(((size_t)N + 1) * 4);
    int*   cursor  = (int*)alloc((size_t)N * 4);          // fallback only
    int2*  ent     = (int2*)alloc(((size_t)M + 64) * 8);  // +64 pad: gather tile prefetch
    int*   bstartT = (int*)alloc((size_t)GB * NBe * 4);   // [k*GB + b]
    int*   bcntT   = (int*)alloc((size_t)GB * NBe * 4);   // [k*GB + b]
    int*   btot    = (int*)alloc(((size_t)NBe + 1) * 4);
    float* Z1      = (float*)alloc((size_t)N * 64 * 4);   // tmp aliases Z1+H (8 MB)
    float* H       = (float*)alloc((size_t)N * 64 * 4);
    float* Z2      = (float*)alloc((size_t)N * 16 * 4);
    (void)ws_size; (void)n_in; (void)out_size;

    // tmp[M] int2 aliases Z1+H (consumed by k_p2 before k_gemm1/k_gather write them)
    int2* tmp = (int2*)Z1;

    float* out = (float*)d_out;

    // fast path also requires tmp (16E bytes) to fit inside Z1+H (512N bytes)
    if (N <= NMAX && GB <= GBMAX && (size_t)16 * E <= (size_t)512 * N) {
        k_p1<<<GB, 1024, 0, stream>>>(ei, ew, E, rsh, NBe, GB, bstartT, bcntT, tmp);
        k_colsum<<<NBe, TPB, 0, stream>>>(bcntT, GB, btot);
        k_p2<<<NBe, 1024, 0, stream>>>(tmp, bstartT, bcntT, btot, GB, rsh, N, NBe, M,
                                       ent, rowptr, dis);
    } else {
        k_init_fb<<<(N + TPB - 1) / TPB, TPB, 0, stream>>>(dis, counts, N);
        k_deg_cnt_fb<<<(E + TPB - 1) / TPB, TPB, 0, stream>>>(ei, ew, dis, counts, E);
        k_rsqrt_fb<<<(N + TPB - 1) / TPB, TPB, 0, stream>>>(dis, N);
        k_scan_fb<<<1, TPB, 0, stream>>>(counts, rowptr, cursor, N);
        k_fill_fb<<<(E + TPB - 1) / TPB, TPB, 0, stream>>>(ei, ew, cursor, ent, E);
    }

    // layer 1
    k_gemm1<<<(N + 3) / 4, TPB, 0, stream>>>(x, W1, dis, Z1, N);
    k_gather<64, true><<<(N + 15) / 16, TPB, 0, stream>>>(Z1, rowptr, (const long long*)ent,
                                                          dis, b1, H, N);
    // layer 2
    k_gemm2<<<(N + 15) / 16, TPB, 0, stream>>>(H, W2, dis, Z2, N);
    k_gather<16, false><<<(N + 63) / 64, TPB, 0, stream>>>(Z2, rowptr, (const long long*)ent,
                                                           dis, b2, out, N);
}

// Round 11
// 156.074 us; speedup vs baseline: 1.0440x; 1.0440x over previous
//
#include <hip/hip_runtime.h>

constexpr int TPB   = 256;    // generic block
constexpr int NMAX  = 16384;  // fast-path cap (node ids fit 20 bits, rloc 6 bits)
constexpr int CHUNK = 2048;   // edges per k_p1 block
constexpr int GBMAX = 1024;   // fast-path cap on p1 grid

// edge_index delivered as int32 [2][E] (validated R3 counters + R6 pass).

// ============ fast path: two-level bucket CSR build, coalesced writes ============
// bucket = node >> rsh (RN = 1<<rsh <= 64 nodes/bucket, NBe = ceil(N/RN) <= 256)
// Tables stored TRANSPOSED [k*GB + b] so column ops are contiguous.

// ---- p1: partition edge-endpoint entries into per-(block,bucket) runs in tmp ----
__global__ __launch_bounds__(1024) void k_p1(const int* __restrict__ ei,
    const float* __restrict__ ew, int E, int rsh, int NBe, int GB,
    int* __restrict__ bstartT, int* __restrict__ bcntT, int2* __restrict__ tmp) {
    __shared__ int cnt[256];
    __shared__ int curs[256];
    __shared__ int sc[256];
    __shared__ int2 stg[2 * CHUNK];   // 32 KB
    int tid = threadIdx.x;
    int b = blockIdx.x;
    int e0 = b * CHUNK;
    int e1 = min(E, e0 + CHUNK);
    if (tid < NBe) cnt[tid] = 0;
    __syncthreads();
    int ea = e0 + tid, ebg = e0 + 1024 + tid;
    int r0 = 0, c0 = 0, r1 = 0, c1 = 0, w0 = 0, w1 = 0;
    bool va = ea < e1, vb = ebg < e1;
    if (va) { r0 = ei[ea];  c0 = ei[E + ea];  w0 = __float_as_int(0.5f * ew[ea]); }
    if (vb) { r1 = ei[ebg]; c1 = ei[E + ebg]; w1 = __float_as_int(0.5f * ew[ebg]); }
    if (va) { atomicAdd(&cnt[r0 >> rsh], 1); atomicAdd(&cnt[c0 >> rsh], 1); }
    if (vb) { atomicAdd(&cnt[r1 >> rsh], 1); atomicAdd(&cnt[c1 >> rsh], 1); }
    __syncthreads();
    int myc = (tid < NBe) ? cnt[tid] : 0;
    if (tid < NBe) sc[tid] = myc;
    __syncthreads();
    for (int off = 1; off < NBe; off <<= 1) {
        int v = 0;
        if (tid < NBe && tid >= off) v = sc[tid - off];
        __syncthreads();
        if (tid < NBe) sc[tid] += v;
        __syncthreads();
    }
    if (tid < NBe) {
        int excl = sc[tid] - myc;
        curs[tid] = excl;
        bstartT[tid * GB + b] = 2 * e0 + excl;   // transposed
        bcntT[tid * GB + b] = myc;
    }
    __syncthreads();
    int mask = (1 << rsh) - 1;
    if (va) {
        int p = atomicAdd(&curs[r0 >> rsh], 1);
        stg[p] = make_int2(((r0 & mask) << 20) | c0, w0);
        p = atomicAdd(&curs[c0 >> rsh], 1);
        stg[p] = make_int2(((c0 & mask) << 20) | r0, w0);
    }
    if (vb) {
        int p = atomicAdd(&curs[r1 >> rsh], 1);
        stg[p] = make_int2(((r1 & mask) << 20) | c1, w1);
        p = atomicAdd(&curs[c1 >> rsh], 1);
        stg[p] = make_int2(((c1 & mask) << 20) | r1, w1);
    }
    __syncthreads();
    int tot = 2 * (e1 - e0);
    for (int i = tid; i < tot; i += 1024) tmp[2 * e0 + i] = stg[i];  // coalesced burst
}

// ---- colsum: one block per bucket, contiguous coalesced row sum -> btot[k] ----
__global__ void k_colsum(const int* __restrict__ bcntT, int GB,
                         int* __restrict__ btot) {
    __shared__ int red[TPB / 64];
    int k = blockIdx.x;
    int s = 0;
    for (int b = threadIdx.x; b < GB; b += TPB) s += bcntT[k * GB + b];
    #pragma unroll
    for (int off = 32; off; off >>= 1) s += __shfl_down(s, off, 64);
    int wv = threadIdx.x >> 6;
    if ((threadIdx.x & 63) == 0) red[wv] = s;
    __syncthreads();
    if (threadIdx.x == 0) {
        int t = 0;
        for (int w = 0; w < TPB / 64; ++w) t += red[w];
        btot[k] = t;
    }
}

// ---- p2: per-bucket two-pass local sort (fused btot scan) -> CSR + rowptr + dis ----
__global__ __launch_bounds__(1024) void k_p2(const int2* __restrict__ tmp,
    const int* __restrict__ bstartT, const int* __restrict__ bcntT,
    const int* __restrict__ btot, int GB, int rsh, int N, int NBe, int M,
    int2* __restrict__ ent, int* __restrict__ rowptr, float* __restrict__ dis) {
    __shared__ int sco[256];
    __shared__ int ncnt[256];
    __shared__ int nstart[256];
    __shared__ int ncur[256];
    __shared__ float wsum[256];
    int k = blockIdx.x;
    int tid = threadIdx.x;
    int RN = 1 << rsh;
    int n0 = k << rsh;
    // fused: exclusive scan of btot -> eb (1 KB, each block does it locally)
    int bt = (tid < NBe) ? btot[tid] : 0;
    if (tid < 256) sco[tid] = bt;
    if (tid < RN) { ncnt[tid] = 0; wsum[tid] = 0.f; }
    __syncthreads();
    for (int off = 1; off < 256; off <<= 1) {
        int v = 0;
        if (tid < 256 && tid >= off) v = sco[tid - off];
        __syncthreads();
        if (tid < 256) sco[tid] += v;
        __syncthreads();
    }
    int eb = sco[k] - btot[k];
    int grp = tid >> 2, sub = tid & 3;  // 4 threads per source block segment
    // Phase A: node-local histogram
    for (int b = grp; b < GB; b += 256) {
        int s = bstartT[k * GB + b];
        int l = bcntT[k * GB + b];
        for (int u = sub; u < l; u += 4) {
            int2 v = tmp[s + u];
            atomicAdd(&ncnt[v.x >> 20], 1);
        }
    }
    __syncthreads();
    int myc = (tid < RN) ? ncnt[tid] : 0;
    if (tid < RN) nstart[tid] = myc;
    __syncthreads();
    for (int off = 1; off < RN; off <<= 1) {
        int v = 0;
        if (tid < RN && tid >= off) v = nstart[tid - off];
        __syncthreads();
        if (tid < RN) nstart[tid] += v;
        __syncthreads();
    }
    if (tid < RN) { nstart[tid] -= myc; ncur[tid] = nstart[tid]; }
    __syncthreads();
    // Phase B: scatter into bucket's contiguous CSR region + weight sums
    for (int b = grp; b < GB; b += 256) {
        int s = bstartT[k * GB + b];
        int l = bcntT[k * GB + b];
        for (int u = sub; u < l; u += 4) {
            int2 v = tmp[s + u];
            int rl = v.x >> 20;
            int cc = v.x & 0xFFFFF;
            int p = atomicAdd(&ncur[rl], 1);
            ent[eb + p] = make_int2(cc, v.y);
            atomicAdd(&wsum[rl], __int_as_float(v.y));  // LDS float atomic
        }
    }
    __syncthreads();
    if (tid < RN && n0 + tid < N) {
        rowptr[n0 + tid] = eb + nstart[tid];
        dis[n0 + tid] = rsqrtf(1.f + wsum[tid]);
    }
    if (k == 0 && tid == 0) rowptr[N] = M;
}

// ============ fallback path: global-atomic prep ============
__global__ void k_init_fb(float* deg, int* counts, int N) {
    int i = blockIdx.x * TPB + threadIdx.x;
    if (i < N) { deg[i] = 1.0f; counts[i] = 0; }
}
__global__ void k_deg_cnt_fb(const int* __restrict__ ei, const float* __restrict__ ew,
                             float* deg, int* counts, int E) {
    int e = blockIdx.x * TPB + threadIdx.x;
    if (e >= E) return;
    int r = ei[e], c = ei[E + e];
    float hw = 0.5f * ew[e];
    unsafeAtomicAdd(&deg[r], hw);
    unsafeAtomicAdd(&deg[c], hw);
    atomicAdd(&counts[r], 1);
    atomicAdd(&counts[c], 1);
}
__global__ void k_rsqrt_fb(float* degdis, int N) {
    int i = blockIdx.x * TPB + threadIdx.x;
    if (i < N) {
        float d = degdis[i];
        degdis[i] = d > 0.f ? rsqrtf(d) : 0.f;
    }
}
__global__ void k_scan_fb(const int* __restrict__ counts, int* __restrict__ rowptr,
                          int* __restrict__ cursor, int N) {
    __shared__ int partial[TPB];
    int tid = threadIdx.x;
    int chunk = (N + TPB - 1) / TPB;
    int begin = tid * chunk;
    int end = begin + chunk; if (end > N) end = N;
    int s = 0;
    for (int i = begin; i < end; ++i) s += counts[i];
    partial[tid] = s;
    __syncthreads();
    for (int off = 1; off < TPB; off <<= 1) {
        int v = partial[tid];
        int add = (tid >= off) ? partial[tid - off] : 0;
        __syncthreads();
        partial[tid] = v + add;
        __syncthreads();
    }
    int base = (tid == 0) ? 0 : partial[tid - 1];
    for (int i = begin; i < end; ++i) {
        rowptr[i] = base; cursor[i] = base;
        base += counts[i];
    }
    if (tid == TPB - 1) rowptr[N] = base;
}
__global__ void k_fill_fb(const int* __restrict__ ei, const float* __restrict__ ew,
                          int* cursor, int2* __restrict__ ent, int E) {
    int e = blockIdx.x * TPB + threadIdx.x;
    if (e >= E) return;
    int r = ei[e], c = ei[E + e];
    int hw = __float_as_int(0.5f * ew[e]);
    int p1 = atomicAdd(&cursor[r], 1);
    ent[p1] = make_int2(c, hw);
    int p2 = atomicAdd(&cursor[c], 1);
    ent[p2] = make_int2(r, hw);
}

// ---------------- Z1[N,64] = dis .* (X[N,64] @ W1[64,64]) ----------------
__global__ void k_gemm1(const float* __restrict__ X, const float* __restrict__ W,
                        const float* __restrict__ dis, float* __restrict__ Z, int N) {
    __shared__ float Wl[64 * 64];
    int tid = threadIdx.x;
    #pragma unroll
    for (int i = tid; i < 4096; i += TPB) Wl[i] = W[i];
    __syncthreads();
    int row = blockIdx.x * 4 + (tid >> 6);
    int f = tid & 63;
    if (row >= N) return;
    const float* xr = X + row * 64;
    float s = 0.f;
    #pragma unroll
    for (int k = 0; k < 64; ++k) s = fmaf(xr[k], Wl[k * 64 + f], s);
    Z[row * 64 + f] = dis[row] * s;
}

// ---- gather: scalar lanes (D lanes/node), pipelined tiles, 16-deep load batches ----
template <int D, bool RELU>
__global__ void k_gather(const float* __restrict__ Z, const int* __restrict__ rowptr,
                         const long long* __restrict__ entq, const float* __restrict__ dis,
                         const float* __restrict__ bias, float* __restrict__ out, int N) {
    constexpr int NPB = TPB / D;
    constexpr int UN = 16;                      // outstanding neighbor rows per batch
    int node = blockIdx.x * NPB + threadIdx.x / D;
    int f = threadIdx.x % D;
    int lane = threadIdx.x & 63;
    int base = lane & ~(D - 1);
    if (node >= N) return;
    int j0 = rowptr[node], j1 = rowptr[node + 1];
    float acc = Z[node * D + f];
    long long cur = 0;
    if (j0 < j1) cur = __builtin_nontemporal_load(entq + j0 + f);  // ent padded by 64
    for (int jb = j0; jb < j1; jb += D) {
        long long nxt = cur;
        if (jb + D < j1) nxt = __builtin_nontemporal_load(entq + jb + D + f);
        int ex = (int)cur;
        float ey = __int_as_float((int)(cur >> 32));
        int cnt = j1 - jb; if (cnt > D) cnt = D;
        int k = 0;
        for (; k + UN <= cnt; k += UN) {
            int n[UN]; float w[UN], z[UN];
            #pragma unroll
            for (int u = 0; u < UN; ++u) {
                n[u] = __shfl(ex, base + k + u);
                w[u] = __shfl(ey, base + k + u);
            }
            #pragma unroll
            for (int u = 0; u < UN; ++u) z[u] = Z[n[u] * D + f];  // 16 rows in flight
            #pragma unroll
            for (int u = 0; u < UN; ++u) acc = fmaf(w[u], z[u], acc);
        }
        for (; k < cnt; ++k) {
            int n0 = __shfl(ex, base + k);
            float w0 = __shfl(ey, base + k);
            acc = fmaf(w0, Z[n0 * D + f], acc);
        }
        cur = nxt;
    }
    float v = fmaf(dis[node], acc, bias[f]);
    if (RELU) v = v > 0.f ? v : 0.f;
    out[node * D + f] = v;
}

// ---------------- Z2[N,16] = dis .* (H[N,64] @ W2[64,16]) ----------------
__global__ void k_gemm2(const float* __restrict__ H, const float* __restrict__ W2,
                        const float* __restrict__ dis, float* __restrict__ Z2, int N) {
    __shared__ float Wl[64 * 16];
    int tid = threadIdx.x;
    #pragma unroll
    for (int i = tid; i < 1024; i += TPB) Wl[i] = W2[i];
    __syncthreads();
    int row = blockIdx.x * 16 + (tid >> 4);
    int f = tid & 15;
    if (row >= N) return;
    const float* hr = H + row * 64;
    float s = 0.f;
    #pragma unroll
    for (int k = 0; k < 64; ++k) s = fmaf(hr[k], Wl[k * 16 + f], s);
    Z2[row * 16 + f] = dis[row] * s;
}

extern "C" void kernel_launch(void* const* d_in, const int* in_sizes, int n_in,
                              void* d_out, int out_size, void* d_ws, size_t ws_size,
                              hipStream_t stream) {
    const float* x  = (const float*)d_in[0];
    const float* W1 = (const float*)d_in[1];
    const float* b1 = (const float*)d_in[2];
    const float* W2 = (const float*)d_in[3];
    const float* b2 = (const float*)d_in[4];
    const float* ew = (const float*)d_in[5];
    const int*   ei = (const int*)d_in[6];   // int32 layout (validated)

    const int N = in_sizes[0] / 64;   // 16384
    const int E = in_sizes[5];        // 524288
    const int M = 2 * E;              // CSR entries

    // bucket geometry: RN = pow2 <= 64, NBe = ceil(N/RN) <= 256
    int rsh = 0;
    while ((256 << rsh) < N) ++rsh;
    const int NBe = (N + (1 << rsh) - 1) >> rsh;
    const int GB  = (E + CHUNK - 1) / CHUNK;

    char* ws = (char*)d_ws;
    size_t off = 0;
    auto alloc = [&](size_t bytes) -> void* {
        void* p = ws + off;
        off += (bytes + 255) & ~(size_t)255;
        return p;
    };
    float* dis     = (float*)alloc((size_t)N * 4);
    int*   counts  = (int*)alloc((size_t)N * 4);          // fallback only
    int*   rowptr  = (int*)alloc(((size_t)N + 1) * 4);
    int*   cursor  = (int*)alloc((size_t)N * 4);          // fallback only
    int2*  ent     = (int2*)alloc(((size_t)M + 64) * 8);  // +64 pad: gather tile prefetch
    int*   bstartT = (int*)alloc((size_t)GB * NBe * 4);   // [k*GB + b]
    int*   bcntT   = (int*)alloc((size_t)GB * NBe * 4);   // [k*GB + b]
    int*   btot    = (int*)alloc(((size_t)NBe + 1) * 4);
    float* Z1      = (float*)alloc((size_t)N * 64 * 4);   // tmp aliases Z1+H (8 MB)
    float* H       = (float*)alloc((size_t)N * 64 * 4);
    float* Z2      = (float*)alloc((size_t)N * 16 * 4);
    (void)ws_size; (void)n_in; (void)out_size;

    // tmp[M] int2 aliases Z1+H (consumed by k_p2 before k_gemm1/k_gather write them)
    int2* tmp = (int2*)Z1;

    float* out = (float*)d_out;

    // fast path requires tmp (16E bytes) to fit inside Z1+H (512N bytes)
    if (N <= NMAX && GB <= GBMAX && (size_t)16 * E <= (size_t)512 * N) {
        k_p1<<<GB, 1024, 0, stream>>>(ei, ew, E, rsh, NBe, GB, bstartT, bcntT, tmp);
        k_colsum<<<NBe, TPB, 0, stream>>>(bcntT, GB, btot);
        k_p2<<<NBe, 1024, 0, stream>>>(tmp, bstartT, bcntT, btot, GB, rsh, N, NBe, M,
                                       ent, rowptr, dis);
    } else {
        k_init_fb<<<(N + TPB - 1) / TPB, TPB, 0, stream>>>(dis, counts, N);
        k_deg_cnt_fb<<<(E + TPB - 1) / TPB, TPB, 0, stream>>>(ei, ew, dis, counts, E);
        k_rsqrt_fb<<<(N + TPB - 1) / TPB, TPB, 0, stream>>>(dis, N);
        k_scan_fb<<<1, TPB, 0, stream>>>(counts, rowptr, cursor, N);
        k_fill_fb<<<(E + TPB - 1) / TPB, TPB, 0, stream>>>(ei, ew, cursor, ent, E);
    }

    // layer 1  (k_gather<64>: NPB = 256/64 = 4 nodes/block -> grid (N+3)/4)
    k_gemm1<<<(N + 3) / 4, TPB, 0, stream>>>(x, W1, dis, Z1, N);
    k_gather<64, true><<<(N + 3) / 4, TPB, 0, stream>>>(Z1, rowptr, (const long long*)ent,
                                                        dis, b1, H, N);
    // layer 2  (k_gather<16>: NPB = 256/16 = 16 nodes/block -> grid (N+15)/16)
    k_gemm2<<<(N + 15) / 16, TPB, 0, stream>>>(H, W2, dis, Z2, N);
    k_gather<16, false><<<(N + 15) / 16, TPB, 0, stream>>>(Z2, rowptr, (const long long*)ent,
                                                           dis, b2, out, N);
}